// Round 9
// baseline (232.325 us; speedup 1.0000x reference)
//
#include <hip/hip_runtime.h>
#include <cstdint>
#include <cmath>

typedef _Float16 f16;
typedef _Float16 f16x4 __attribute__((ext_vector_type(4)));
typedef _Float16 f16x8 __attribute__((ext_vector_type(8)));
typedef float f32x4 __attribute__((ext_vector_type(4)));
typedef float f32x16 __attribute__((ext_vector_type(16)));
typedef uint32_t u32;
typedef uint32_t u32x4 __attribute__((ext_vector_type(4)));

#define DEVI static __device__ __forceinline__

constexpr int S  = 4096;
constexpr int DM = 1024;   // model dim
constexpr int NH = 16;     // heads
constexpr int HD = 64;     // head dim
constexpr float LOG2E = 1.44269504f;

// ---- async global->LDS (16B/lane, dest = uniform base + lane*16) ----
DEVI void gll16(const f16* g, f16* l) {
  __builtin_amdgcn_global_load_lds((const __attribute__((address_space(1))) void*)g,
                                   (__attribute__((address_space(3))) void*)l, 16, 0, 0);
}
DEVI void wait_vm0() { asm volatile("s_waitcnt vmcnt(0)" ::: "memory"); }
DEVI u32 pkrtz(float a, float b) {
  auto h = __builtin_amdgcn_cvt_pkrtz(a, b);   // __fp16 ext_vector_type(2)
  return __builtin_bit_cast(u32, h);
}
#define MAX3(a,b,c) fmaxf(fmaxf(a,b),c)

// ---- transpose + f32->f16 convert: src[R][C] f32 -> dst[C][R] f16 ----
__global__ void k_tcvt(const float* __restrict__ src, f16* __restrict__ dst, int R, int C) {
  __shared__ float t[32][33];
  const int c = threadIdx.x & 31, r0 = threadIdx.x >> 5;
  const int bc = blockIdx.x * 32, br = blockIdx.y * 32;
#pragma unroll
  for (int p = 0; p < 4; p++)
    t[r0 + p*8][c] = src[(size_t)(br + r0 + p*8) * C + bc + c];
  __syncthreads();
#pragma unroll
  for (int p = 0; p < 4; p++)
    dst[(size_t)(bc + r0 + p*8) * R + br + c] = (f16)t[c][r0 + p*8];
}

// ---- mask [4096][4096] int32 -> bitmask TRANSPOSED [128 kv-words][4096 q] ----
__global__ void k_maskbits(const int* __restrict__ m, u32* __restrict__ bits) {
  const int idx = blockIdx.x * 256 + threadIdx.x;   // 0..524287
  const int q = idx & 4095, wc = idx >> 12;         // wc = kv-word 0..127
  const int4* p = (const int4*)(m + (size_t)q * 4096 + wc * 32);
  u32 wv = 0;
#pragma unroll
  for (int j = 0; j < 8; j++) {
    int4 x = p[j];
    wv |= (x.x != 0 ? 1u : 0u) << (4*j + 0);
    wv |= (x.y != 0 ? 1u : 0u) << (4*j + 1);
    wv |= (x.z != 0 ? 1u : 0u) << (4*j + 2);
    wv |= (x.w != 0 ? 1u : 0u) << (4*j + 3);
  }
  bits[(size_t)wc * 4096 + q] = wv;
}

// ---- GEMM: C[M][N] = A[M][1024] * Bt[N][1024]^T + bias (big: Q and O proj) ----
// EPI 0: f16 out scaled by log2e (Q-proj feeding attention exp2 domain)
// EPI 1: f32 out + bias
template<int BN, int NWM, int NWN, bool A16, int EPI>
__launch_bounds__(256)
__global__ void k_gemm(const float* __restrict__ Af, const f16* __restrict__ Ah,
                       const f16* __restrict__ Bt, const float* __restrict__ bias,
                       float* __restrict__ Cf, f16* __restrict__ Ch)
{
  constexpr int BM = 128, BK = 32, K = 1024, NW = 4;
  constexpr int WM = BM / NWM, WN = BN / NWN;
  constexpr int MM = WM / 16, NN = WN / 16;
  __shared__ __align__(16) f16 As[BM * BK];
  __shared__ __align__(16) f16 Bs[BN * BK];
  const int tid = threadIdx.x, l = tid & 63, w = tid >> 6;
  const int m0 = blockIdx.x * BM, n0 = blockIdx.y * BN;
  const int wm = (w / NWN) * WM, wn = (w % NWN) * WN;
  f32x4 acc[MM][NN] = {};

  for (int k0 = 0; k0 < K; k0 += BK) {
    if constexpr (A16) {
#pragma unroll
      for (int rep = 0; rep < 2; rep++) {
        int I = w * 2 + rep;
        gll16(Ah + (size_t)(m0 + I*16 + (l >> 2)) * K + k0 + (l & 3) * 8, &As[I * 512]);
      }
    } else {
#pragma unroll
      for (int rep = 0; rep < 2; rep++) {
        int row = (tid >> 2) + rep * 64, ko = (tid & 3) * 8;
        const float4* src = (const float4*)(Af + (size_t)(m0 + row) * K + k0 + ko);
        float4 a = src[0], b = src[1];
        f16x8 hv = { (f16)a.x,(f16)a.y,(f16)a.z,(f16)a.w,(f16)b.x,(f16)b.y,(f16)b.z,(f16)b.w };
        *(f16x8*)(&As[row * BK + ko]) = hv;
      }
    }
    constexpr int BI = (BN * BK * 2) / 1024;
#pragma unroll
    for (int rep = 0; rep < BI / NW; rep++) {
      int I = w * (BI / NW) + rep;
      gll16(Bt + (size_t)(n0 + I*16 + (l >> 2)) * K + k0 + (l & 3) * 8, &Bs[I * 512]);
    }
    wait_vm0();
    __syncthreads();
    f16x8 af[MM], bf[NN];
#pragma unroll
    for (int i = 0; i < MM; i++)
      af[i] = *(const f16x8*)(&As[(wm + i*16 + (l & 15)) * BK + (l >> 4) * 8]);
#pragma unroll
    for (int j = 0; j < NN; j++)
      bf[j] = *(const f16x8*)(&Bs[(wn + j*16 + (l & 15)) * BK + (l >> 4) * 8]);
    __builtin_amdgcn_s_setprio(1);
#pragma unroll
    for (int i = 0; i < MM; i++)
#pragma unroll
      for (int j = 0; j < NN; j++)
        acc[i][j] = __builtin_amdgcn_mfma_f32_16x16x32_f16(af[i], bf[j], acc[i][j], 0, 0, 0);
    __builtin_amdgcn_s_setprio(0);
    __syncthreads();
  }
#pragma unroll
  for (int i = 0; i < MM; i++)
#pragma unroll
    for (int j = 0; j < NN; j++)
#pragma unroll
      for (int r = 0; r < 4; r++) {
        int row = m0 + wm + i*16 + (l >> 4) * 4 + r;
        int col = n0 + wn + j*16 + (l & 15);
        float vv = acc[i][j][r] + bias[col];
        if constexpr (EPI == 0) Ch[(size_t)row * 1024 + col] = (f16)(vv * LOG2E);
        if constexpr (EPI == 1) Cf[(size_t)row * 1024 + col] = vv;
      }
}

// ---- fused K+V projection: BM=32 tiles, grid (128, 2) -> 256 WGs ----
__launch_bounds__(256)
__global__ void k_gemm_kv(const float* __restrict__ kin, const float* __restrict__ vin,
                          const f16* __restrict__ Wkt, const f16* __restrict__ Wvt,
                          const float* __restrict__ bkp, const float* __restrict__ bvp,
                          float* __restrict__ khf, float* __restrict__ vhf,
                          f16* __restrict__ khp, f16* __restrict__ vtp)
{
  constexpr int BM = 32, BK = 32, K = 1024;
  const bool isV = (blockIdx.y != 0);
  const float* A   = isV ? vin : kin;
  const f16*  Bt   = isV ? Wvt : Wkt;
  const float* bia = isV ? bvp : bkp;
  __shared__ __align__(16) f16 As[BM * BK];
  __shared__ __align__(16) f16 Bs[64 * BK];
  const int tid = threadIdx.x, l = tid & 63, w = tid >> 6;
  const int m0 = blockIdx.x * BM;
  const int wm = (w >> 1) * 16, wn = (w & 1) * 32;
  f32x4 acc[2] = {};

  for (int k0 = 0; k0 < K; k0 += BK) {
    {
      int row = tid >> 3, ko = (tid & 7) * 4;
      float4 a = *(const float4*)(A + (size_t)(m0 + row) * K + k0 + ko);
      f16x4 hv = { (f16)a.x, (f16)a.y, (f16)a.z, (f16)a.w };
      *(f16x4*)(&As[row * BK + ko]) = hv;
    }
    gll16(Bt + (size_t)(w*16 + (l >> 2)) * K + k0 + (l & 3) * 8, &Bs[w * 512]);
    wait_vm0();
    __syncthreads();
    f16x8 af = *(const f16x8*)(&As[(wm + (l & 15)) * BK + (l >> 4) * 8]);
#pragma unroll
    for (int j = 0; j < 2; j++) {
      f16x8 bf = *(const f16x8*)(&Bs[(wn + j*16 + (l & 15)) * BK + (l >> 4) * 8]);
      acc[j] = __builtin_amdgcn_mfma_f32_16x16x32_f16(af, bf, acc[j], 0, 0, 0);
    }
    __syncthreads();
  }
#pragma unroll
  for (int j = 0; j < 2; j++)
#pragma unroll
    for (int r = 0; r < 4; r++) {
      int row = m0 + wm + (l >> 4) * 4 + r;
      int col = wn + j*16 + (l & 15);
      float vv = acc[j][r] + bia[col];
      if (!isV) { khf[(size_t)row * 64 + col] = vv; khp[(size_t)row * 64 + col] = (f16)vv; }
      else      { vhf[(size_t)row * 64 + col] = vv; vtp[(size_t)col * S + row] = (f16)vv; }
    }
}

// ---- fused MQA flash attention, in-WG split-KV, O^T accumulators ----
// grid (128, 4); 512 threads = 8 waves = 4 heads x 2 kv-halves.
// Scores in log2 domain (Q pre-scaled by log2e). Swapped QK^T (scores[kv][q]);
// PV as O^T = mfma(V, P) -> acc cols = q = own lane; VALU lsum (R5 structure).
// Mask -> -1e30 BEFORE max (R5 semantics).
__launch_bounds__(512, 4)
__global__ void k_attn(const f16* __restrict__ qh, const f16* __restrict__ kh,
                       const f16* __restrict__ vt, const u32* __restrict__ mb,
                       f16* __restrict__ att)
{
  constexpr int KB = 64, HALF = 2048, NIT = HALF / KB;   // 32 iters per half
  __shared__ __align__(16) char SM[81920];
  f16* Qs = (f16*)SM;                    // [4 heads][32 q][64 d] swizzled, 16 KB
  f16* Ks = (f16*)(SM + 16384);          // [kvh][buf][64*64] swizzled, 32 KB
  f16* Vs = (f16*)(SM + 49152);          // [kvh][buf][64*64] swizzled, 32 KB
  float* Macc = (float*)(SM + 16384);    // merge overlay (over Ks): [4 heads][64 d][32 q]
  float* Mml  = (float*)(SM + 49152);    // overlay (over Vs): [4 heads][64]

  const int tid = threadIdx.x, l = tid & 63, w = tid >> 6;
  const int kvh = w >> 2, wh = w & 3;
  const int lq = l & 31, hi = l >> 5;
  const int h  = blockIdx.y * 4 + wh;
  const int q0 = blockIdx.x * 32;
  const int kvb = kvh * HALF;

  const int sch = (l & 7) ^ (l >> 3);    // base source-chunk swizzle ((row&7) part)
  const int s0  = (lq & 7) ^ (lq >> 3);  // read swizzle for row lq
  const int s1  = s0 ^ 4;                // row 32+lq

  // ---- stage Q once (kvh==0 waves): head wh, rows q0..q0+31; row = 8p+(l>>3)
  if (kvh == 0) {
#pragma unroll
    for (int p = 0; p < 4; p++)
      gll16(qh + (size_t)(q0 + 8*p + (l >> 3)) * DM + h * HD + (sch ^ p) * 8,
            Qs + wh * 2048 + p * 512);
  }
  // ---- stage first K/V tile of this wave's half; row = 16wh+8j+(l>>3)
  f16* KsH = Ks + kvh * 8192;
  f16* VsH = Vs + kvh * 8192;
#pragma unroll
  for (int j = 0; j < 2; j++) {
    const int row = 16*wh + 8*j + (l >> 3);
    const int sc = sch ^ (2*wh + j);
    gll16(kh + (size_t)(kvb + row) * HD + sc * 8, KsH + (2*wh + j) * 512);
    gll16(vt + (size_t)row * S + kvb + sc * 8,    VsH + (2*wh + j) * 512);
  }
  wait_vm0();
  __syncthreads();

  f32x16 acc0 = {}, acc1 = {};
  float mrun = -1e29f, lsum = 0.f;
  const f16* QsW = Qs + wh * 2048;

  for (int it = 0; it < NIT; ++it) {
    const int cur = it & 1;
    const int wd = (kvb >> 5) + it * 2;
    u32 mw0 = mb[(size_t)wd * S + q0 + lq];
    u32 mw1 = mb[(size_t)(wd + 1) * S + q0 + lq];
    if (it + 1 < NIT) {
      const int nk = kvb + (it + 1) * KB;
#pragma unroll
      for (int j = 0; j < 2; j++) {
        const int row = 16*wh + 8*j + (l >> 3);
        const int sc = sch ^ (2*wh + j);
        gll16(kh + (size_t)(nk + row) * HD + sc * 8, KsH + (cur ^ 1) * 4096 + (2*wh + j) * 512);
        gll16(vt + (size_t)row * S + nk + sc * 8,    VsH + (cur ^ 1) * 4096 + (2*wh + j) * 512);
      }
    }
    // QK^T swapped: A = K rows (kv), B = Q  -> t[kv][q], lane col q = lq
    f32x16 t0 = {}, t1 = {};
    const f16* KT = KsH + cur * 4096;
    __builtin_amdgcn_s_setprio(1);
#pragma unroll
    for (int c = 0; c < 4; c++) {
      const int u = hi + 2 * c;
      f16x8 qfc = *(const f16x8*)(QsW + lq * 64 + ((u ^ s0) << 3));
      f16x8 kf0 = *(const f16x8*)(KT + lq * 64        + ((u ^ s0) << 3));
      f16x8 kf1 = *(const f16x8*)(KT + (32 + lq) * 64 + ((u ^ s1) << 3));
      t0 = __builtin_amdgcn_mfma_f32_32x32x16_f16(kf0, qfc, t0, 0, 0, 0);
      t1 = __builtin_amdgcn_mfma_f32_32x32x16_f16(kf1, qfc, t1, 0, 0, 0);
    }
    __builtin_amdgcn_s_setprio(0);
    // mask -> -1e30 before max (R5 semantics)
    const u32 b0 = mw0 >> (4 * hi), b1 = mw1 >> (4 * hi);
#pragma unroll
    for (int r = 0; r < 16; r++) {
      const int bp = (r & 3) + 8 * (r >> 2);
      t0[r] = ((b0 >> bp) & 1) ? -1e30f : t0[r];
      t1[r] = ((b1 >> bp) & 1) ? -1e30f : t1[r];
    }
    // row max (q = lq), v_max3 tree
    float z0 = MAX3(t0[0], t0[1],  t0[2]),  z1 = MAX3(t0[3],  t0[4],  t0[5]);
    float z2 = MAX3(t0[6], t0[7],  t0[8]),  z3 = MAX3(t0[9],  t0[10], t0[11]);
    float z4 = MAX3(t0[12],t0[13], t0[14]), z5 = MAX3(t0[15], t1[0],  t1[1]);
    float z6 = MAX3(t1[2], t1[3],  t1[4]),  z7 = MAX3(t1[5],  t1[6],  t1[7]);
    float z8 = MAX3(t1[8], t1[9],  t1[10]), z9 = MAX3(t1[11], t1[12], t1[13]);
    float za = fmaxf(t1[14], t1[15]);
    float y0 = MAX3(z0, z1, z2), y1 = MAX3(z3, z4, z5), y2 = MAX3(z6, z7, z8);
    float pmax = MAX3(y0, y1, fmaxf(y2, fmaxf(z9, za)));
    pmax = fmaxf(pmax, __shfl_xor(pmax, 32));
    if (!__all(pmax <= mrun + 11.6f)) {    // defer-max (log2 domain); shuffle-free rescale
      float mn = fmaxf(mrun, pmax);
      float sc = exp2f(mrun - mn);
      mrun = mn; lsum *= sc;
#pragma unroll
      for (int r = 0; r < 16; r++) { acc0[r] *= sc; acc1[r] *= sc; }
    }
#pragma unroll
    for (int r = 0; r < 16; r++) {
      t0[r] = exp2f(t0[r] - mrun);
      t1[r] = exp2f(t1[r] - mrun);
    }
    {
      float a0s = 0.f, a1s = 0.f, a2s = 0.f, a3s = 0.f;
#pragma unroll
      for (int r = 0; r < 16; r += 4) {
        a0s += t0[r] + t1[r];       a1s += t0[r+1] + t1[r+1];
        a2s += t0[r+2] + t1[r+2];   a3s += t0[r+3] + t1[r+3];
      }
      float rs = (a0s + a1s) + (a2s + a3s);
      rs += __shfl_xor(rs, 32);
      lsum += rs;
    }
    // PV (O^T): per c build pa = P[kv=16c+8hi+e][q=lq] via pkrtz+permlane
    const f16* VT = VsH + cur * 4096;
#pragma unroll
    for (int c = 0; c < 4; c++) {
      const int cc = c & 1;
      u32 w0, w1, w2, w3;
      if (c < 2) {
        w0 = pkrtz(t0[8*cc + 0], t0[8*cc + 1]);  w2 = pkrtz(t0[8*cc + 4], t0[8*cc + 5]);
        w1 = pkrtz(t0[8*cc + 2], t0[8*cc + 3]);  w3 = pkrtz(t0[8*cc + 6], t0[8*cc + 7]);
      } else {
        w0 = pkrtz(t1[8*cc + 0], t1[8*cc + 1]);  w2 = pkrtz(t1[8*cc + 4], t1[8*cc + 5]);
        w1 = pkrtz(t1[8*cc + 2], t1[8*cc + 3]);  w3 = pkrtz(t1[8*cc + 6], t1[8*cc + 7]);
      }
      asm volatile("v_permlane32_swap_b32 %0, %1" : "+v"(w0), "+v"(w2));
      asm volatile("v_permlane32_swap_b32 %0, %1" : "+v"(w1), "+v"(w3));
      u32x4 aw = { w0, w1, w2, w3 };
      f16x8 pa = __builtin_bit_cast(f16x8, aw);
      const int u = hi + 2 * c;
      f16x8 v0 = *(const f16x8*)(VT + lq * 64        + ((u ^ s0) << 3));
      f16x8 v1 = *(const f16x8*)(VT + (32 + lq) * 64 + ((u ^ s1) << 3));
      __builtin_amdgcn_s_setprio(1);
      acc0 = __builtin_amdgcn_mfma_f32_32x32x16_f16(v0, pa, acc0, 0, 0, 0);
      acc1 = __builtin_amdgcn_mfma_f32_32x32x16_f16(v1, pa, acc1, 0, 0, 0);
      __builtin_amdgcn_s_setprio(0);
    }
    wait_vm0();
    __syncthreads();
  }

  // ---- merge halves via LDS overlay; acc layout: O^T[d][q=lq] ----
  if (kvh == 1) {
#pragma unroll
    for (int r = 0; r < 16; r++) {
      const int d0 = (r & 3) + 8 * (r >> 2) + 4 * hi;
      Macc[wh * 2048 + d0 * 32 + lq]        = acc0[r];
      Macc[wh * 2048 + (d0 + 32) * 32 + lq] = acc1[r];
    }
    if (hi == 0) {
      Mml[wh * 64 + lq]      = mrun;
      Mml[wh * 64 + 32 + lq] = lsum;
    }
  }
  __syncthreads();
  if (kvh == 0) {
    const float mB = Mml[wh * 64 + lq];
    const float lB = Mml[wh * 64 + 32 + lq];
    const float mS = fmaxf(mrun, mB);
    const float eA = exp2f(mrun - mS), eB = exp2f(mB - mS);
    const float inv = 1.f / (lsum * eA + lB * eB);
    const float fA = eA * inv, fB = eB * inv;
    const size_t base = (size_t)(q0 + lq) * DM + h * HD;
#pragma unroll
    for (int g = 0; g < 4; g++) {
      f16x4 o0, o1;
#pragma unroll
      for (int j = 0; j < 4; j++) {
        const int r = 4 * g + j, d0 = j + 8 * g + 4 * hi;
        o0[j] = (f16)(acc0[r] * fA + Macc[wh * 2048 + d0 * 32 + lq] * fB);
        o1[j] = (f16)(acc1[r] * fA + Macc[wh * 2048 + (d0 + 32) * 32 + lq] * fB);
      }
      *(f16x4*)(att + base + 8 * g + 4 * hi)      = o0;
      *(f16x4*)(att + base + 32 + 8 * g + 4 * hi) = o1;
    }
  }
}

extern "C" void kernel_launch(void* const* d_in, const int* in_sizes, int n_in,
                              void* d_out, int out_size, void* d_ws, size_t ws_size,
                              hipStream_t stream)
{
  const float* q  = (const float*)d_in[0];
  const float* k  = (const float*)d_in[1];
  const float* v  = (const float*)d_in[2];
  const int*  msk = (const int*)d_in[3];
  const float* Wq = (const float*)d_in[4];
  const float* bq = (const float*)d_in[5];
  const float* Wk = (const float*)d_in[6];
  const float* bk = (const float*)d_in[7];
  const float* Wv = (const float*)d_in[8];
  const float* bv = (const float*)d_in[9];
  const float* Wo = (const float*)d_in[10];
  const float* bo = (const float*)d_in[11];

  float* out = (float*)d_out;                 // [4096][1024]
  float* khf = out + (size_t)S * DM;          // [4096][64]
  float* vhf = khf + (size_t)S * HD;          // [4096][64]

  char* ws = (char*)d_ws;
  f16* Wq_t = (f16*)(ws);                               // [1024][1024]
  f16* Wo_t = (f16*)(ws + (2u  << 20));                 // [1024][1024]
  f16* Wk_t = (f16*)(ws + (4u  << 20));                 // [64][1024]
  f16* Wv_t = (f16*)(ws + (4u  << 20) + (128u << 10));  // [64][1024]
  f16* qhp  = (f16*)(ws + (4u  << 20) + (256u << 10));  // [4096][1024] (log2e-scaled)
  f16* khp  = (f16*)(ws + (12u << 20) + (256u << 10));  // [4096][64]
  f16* vtp  = (f16*)(ws + (12u << 20) + (768u << 10));  // [64][4096]
  f16* attp = (f16*)(ws + (13u << 20) + (256u << 10));  // [4096][1024]
  u32* mbp  = (u32*)(ws + (21u << 20) + (256u << 10));  // [128][4096] transposed bits

  k_tcvt<<<dim3(32, 32), 256, 0, stream>>>(Wq, Wq_t, 1024, 1024);
  k_tcvt<<<dim3(32, 32), 256, 0, stream>>>(Wo, Wo_t, 1024, 1024);
  k_tcvt<<<dim3(2, 32),  256, 0, stream>>>(Wk, Wk_t, 1024, 64);
  k_tcvt<<<dim3(2, 32),  256, 0, stream>>>(Wv, Wv_t, 1024, 64);
  k_maskbits<<<2048, 256, 0, stream>>>(msk, mbp);

  k_gemm<128, 2, 2, false, 0><<<dim3(32, 8), 256, 0, stream>>>(q, nullptr, Wq_t, bq, nullptr, qhp);
  k_gemm_kv<<<dim3(128, 2), 256, 0, stream>>>(k, v, Wk_t, Wv_t, bk, bv, khf, vhf, khp, vtp);

  k_attn<<<dim3(S / 32, 4), 512, 0, stream>>>(qhp, khp, vtp, mbp, attp);

  k_gemm<128, 2, 2, true, 1><<<dim3(32, 8), 256, 0, stream>>>(nullptr, attp, Wo_t, bo, out, nullptr);
}

// Round 10
// 208.916 us; speedup vs baseline: 1.1121x; 1.1121x over previous
//
#include <hip/hip_runtime.h>
#include <cstdint>
#include <cmath>

typedef _Float16 f16;
typedef _Float16 f16x4 __attribute__((ext_vector_type(4)));
typedef _Float16 f16x8 __attribute__((ext_vector_type(8)));
typedef float f32x4 __attribute__((ext_vector_type(4)));
typedef float f32x16 __attribute__((ext_vector_type(16)));
typedef uint32_t u32;
typedef uint32_t u32x4 __attribute__((ext_vector_type(4)));

#define DEVI static __device__ __forceinline__

constexpr int S  = 4096;
constexpr int DM = 1024;   // model dim
constexpr int NH = 16;     // heads
constexpr int HD = 64;     // head dim
constexpr float LOG2E = 1.44269504f;

// ---- async global->LDS (16B/lane, dest = uniform base + lane*16) ----
DEVI void gll16(const f16* g, f16* l) {
  __builtin_amdgcn_global_load_lds((const __attribute__((address_space(1))) void*)g,
                                   (__attribute__((address_space(3))) void*)l, 16, 0, 0);
}
DEVI void wait_vm0() { asm volatile("s_waitcnt vmcnt(0)" ::: "memory"); }
DEVI u32 pkrtz(float a, float b) {
  auto h = __builtin_amdgcn_cvt_pkrtz(a, b);   // __fp16 ext_vector_type(2)
  return __builtin_bit_cast(u32, h);
}
DEVI float exp2n(float x) { return __builtin_amdgcn_exp2f(x); }  // native v_exp_f32
#define MAX3(a,b,c) fmaxf(fmaxf(a,b),c)

// ---- transpose + f32->f16 convert: src[R][C] f32 -> dst[C][R] f16 ----
__global__ void k_tcvt(const float* __restrict__ src, f16* __restrict__ dst, int R, int C) {
  __shared__ float t[32][33];
  const int c = threadIdx.x & 31, r0 = threadIdx.x >> 5;
  const int bc = blockIdx.x * 32, br = blockIdx.y * 32;
#pragma unroll
  for (int p = 0; p < 4; p++)
    t[r0 + p*8][c] = src[(size_t)(br + r0 + p*8) * C + bc + c];
  __syncthreads();
#pragma unroll
  for (int p = 0; p < 4; p++)
    dst[(size_t)(bc + r0 + p*8) * R + br + c] = (f16)t[c][r0 + p*8];
}

// ---- mask [4096][4096] int32 -> bitmask TRANSPOSED [128 kv-words][4096 q] ----
__global__ void k_maskbits(const int* __restrict__ m, u32* __restrict__ bits) {
  const int idx = blockIdx.x * 256 + threadIdx.x;   // 0..524287
  const int q = idx & 4095, wc = idx >> 12;         // wc = kv-word 0..127
  const int4* p = (const int4*)(m + (size_t)q * 4096 + wc * 32);
  u32 wv = 0;
#pragma unroll
  for (int j = 0; j < 8; j++) {
    int4 x = p[j];
    wv |= (x.x != 0 ? 1u : 0u) << (4*j + 0);
    wv |= (x.y != 0 ? 1u : 0u) << (4*j + 1);
    wv |= (x.z != 0 ? 1u : 0u) << (4*j + 2);
    wv |= (x.w != 0 ? 1u : 0u) << (4*j + 3);
  }
  bits[(size_t)wc * 4096 + q] = wv;
}

// ---- GEMM: C[M][N] = A[M][1024] * Bt[N][1024]^T + bias (big: Q and O proj) ----
// EPI 0: f16 out scaled by log2e (Q-proj feeding attention exp2 domain)
// EPI 1: f32 out + bias
template<int BN, int NWM, int NWN, bool A16, int EPI>
__launch_bounds__(256)
__global__ void k_gemm(const float* __restrict__ Af, const f16* __restrict__ Ah,
                       const f16* __restrict__ Bt, const float* __restrict__ bias,
                       float* __restrict__ Cf, f16* __restrict__ Ch)
{
  constexpr int BM = 128, BK = 32, K = 1024, NW = 4;
  constexpr int WM = BM / NWM, WN = BN / NWN;
  constexpr int MM = WM / 16, NN = WN / 16;
  __shared__ __align__(16) f16 As[BM * BK];
  __shared__ __align__(16) f16 Bs[BN * BK];
  const int tid = threadIdx.x, l = tid & 63, w = tid >> 6;
  const int m0 = blockIdx.x * BM, n0 = blockIdx.y * BN;
  const int wm = (w / NWN) * WM, wn = (w % NWN) * WN;
  f32x4 acc[MM][NN] = {};

  for (int k0 = 0; k0 < K; k0 += BK) {
    if constexpr (A16) {
#pragma unroll
      for (int rep = 0; rep < 2; rep++) {
        int I = w * 2 + rep;
        gll16(Ah + (size_t)(m0 + I*16 + (l >> 2)) * K + k0 + (l & 3) * 8, &As[I * 512]);
      }
    } else {
#pragma unroll
      for (int rep = 0; rep < 2; rep++) {
        int row = (tid >> 2) + rep * 64, ko = (tid & 3) * 8;
        const float4* src = (const float4*)(Af + (size_t)(m0 + row) * K + k0 + ko);
        float4 a = src[0], b = src[1];
        f16x8 hv = { (f16)a.x,(f16)a.y,(f16)a.z,(f16)a.w,(f16)b.x,(f16)b.y,(f16)b.z,(f16)b.w };
        *(f16x8*)(&As[row * BK + ko]) = hv;
      }
    }
    constexpr int BI = (BN * BK * 2) / 1024;
#pragma unroll
    for (int rep = 0; rep < BI / NW; rep++) {
      int I = w * (BI / NW) + rep;
      gll16(Bt + (size_t)(n0 + I*16 + (l >> 2)) * K + k0 + (l & 3) * 8, &Bs[I * 512]);
    }
    wait_vm0();
    __syncthreads();
    f16x8 af[MM], bf[NN];
#pragma unroll
    for (int i = 0; i < MM; i++)
      af[i] = *(const f16x8*)(&As[(wm + i*16 + (l & 15)) * BK + (l >> 4) * 8]);
#pragma unroll
    for (int j = 0; j < NN; j++)
      bf[j] = *(const f16x8*)(&Bs[(wn + j*16 + (l & 15)) * BK + (l >> 4) * 8]);
    __builtin_amdgcn_s_setprio(1);
#pragma unroll
    for (int i = 0; i < MM; i++)
#pragma unroll
      for (int j = 0; j < NN; j++)
        acc[i][j] = __builtin_amdgcn_mfma_f32_16x16x32_f16(af[i], bf[j], acc[i][j], 0, 0, 0);
    __builtin_amdgcn_s_setprio(0);
    __syncthreads();
  }
#pragma unroll
  for (int i = 0; i < MM; i++)
#pragma unroll
    for (int j = 0; j < NN; j++)
#pragma unroll
      for (int r = 0; r < 4; r++) {
        int row = m0 + wm + i*16 + (l >> 4) * 4 + r;
        int col = n0 + wn + j*16 + (l & 15);
        float vv = acc[i][j][r] + bias[col];
        if constexpr (EPI == 0) Ch[(size_t)row * 1024 + col] = (f16)(vv * LOG2E);
        if constexpr (EPI == 1) Cf[(size_t)row * 1024 + col] = vv;
      }
}

// ---- fused K+V projection: BM=32 tiles, grid (128, 2) -> 256 WGs ----
__launch_bounds__(256)
__global__ void k_gemm_kv(const float* __restrict__ kin, const float* __restrict__ vin,
                          const f16* __restrict__ Wkt, const f16* __restrict__ Wvt,
                          const float* __restrict__ bkp, const float* __restrict__ bvp,
                          float* __restrict__ khf, float* __restrict__ vhf,
                          f16* __restrict__ khp, f16* __restrict__ vtp)
{
  constexpr int BM = 32, BK = 32, K = 1024;
  const bool isV = (blockIdx.y != 0);
  const float* A   = isV ? vin : kin;
  const f16*  Bt   = isV ? Wvt : Wkt;
  const float* bia = isV ? bvp : bkp;
  __shared__ __align__(16) f16 As[BM * BK];
  __shared__ __align__(16) f16 Bs[64 * BK];
  const int tid = threadIdx.x, l = tid & 63, w = tid >> 6;
  const int m0 = blockIdx.x * BM;
  const int wm = (w >> 1) * 16, wn = (w & 1) * 32;
  f32x4 acc[2] = {};

  for (int k0 = 0; k0 < K; k0 += BK) {
    {
      int row = tid >> 3, ko = (tid & 7) * 4;
      float4 a = *(const float4*)(A + (size_t)(m0 + row) * K + k0 + ko);
      f16x4 hv = { (f16)a.x, (f16)a.y, (f16)a.z, (f16)a.w };
      *(f16x4*)(&As[row * BK + ko]) = hv;
    }
    gll16(Bt + (size_t)(w*16 + (l >> 2)) * K + k0 + (l & 3) * 8, &Bs[w * 512]);
    wait_vm0();
    __syncthreads();
    f16x8 af = *(const f16x8*)(&As[(wm + (l & 15)) * BK + (l >> 4) * 8]);
#pragma unroll
    for (int j = 0; j < 2; j++) {
      f16x8 bf = *(const f16x8*)(&Bs[(wn + j*16 + (l & 15)) * BK + (l >> 4) * 8]);
      acc[j] = __builtin_amdgcn_mfma_f32_16x16x32_f16(af, bf, acc[j], 0, 0, 0);
    }
    __syncthreads();
  }
#pragma unroll
  for (int j = 0; j < 2; j++)
#pragma unroll
    for (int r = 0; r < 4; r++) {
      int row = m0 + wm + (l >> 4) * 4 + r;
      int col = wn + j*16 + (l & 15);
      float vv = acc[j][r] + bia[col];
      if (!isV) { khf[(size_t)row * 64 + col] = vv; khp[(size_t)row * 64 + col] = (f16)vv; }
      else      { vhf[(size_t)row * 64 + col] = vv; vtp[(size_t)col * S + row] = (f16)vv; }
    }
}

// ---- fused MQA flash attention, in-WG split-KV, O^T accumulators ----
// grid (128, 4); 512 threads = 8 waves = 4 heads x 2 kv-halves.
// Scores in log2 domain (Q pre-scaled by log2e). Swapped QK^T (scores[kv][q]);
// PV as O^T = mfma(V, P) -> acc cols = q = own lane; VALU lsum.
// Mask -> -1e30 BEFORE max. exp = native v_exp_f32.
__launch_bounds__(512, 4)
__global__ void k_attn(const f16* __restrict__ qh, const f16* __restrict__ kh,
                       const f16* __restrict__ vt, const u32* __restrict__ mb,
                       f16* __restrict__ att)
{
  constexpr int KB = 64, HALF = 2048, NIT = HALF / KB;   // 32 iters per half
  __shared__ __align__(16) char SM[81920];
  f16* Qs = (f16*)SM;                    // [4 heads][32 q][64 d] swizzled, 16 KB
  f16* Ks = (f16*)(SM + 16384);          // [kvh][buf][64*64] swizzled, 32 KB
  f16* Vs = (f16*)(SM + 49152);          // [kvh][buf][64*64] swizzled, 32 KB
  float* Macc = (float*)(SM + 16384);    // merge overlay (over Ks): [4 heads][64 d][32 q]
  float* Mml  = (float*)(SM + 49152);    // overlay (over Vs): [4 heads][64]

  const int tid = threadIdx.x, l = tid & 63, w = tid >> 6;
  const int kvh = w >> 2, wh = w & 3;
  const int lq = l & 31, hi = l >> 5;
  const int h  = blockIdx.y * 4 + wh;
  const int q0 = blockIdx.x * 32;
  const int kvb = kvh * HALF;

  const int sch = (l & 7) ^ (l >> 3);    // base source-chunk swizzle ((row&7) part)
  const int s0  = (lq & 7) ^ (lq >> 3);  // read swizzle for row lq
  const int s1  = s0 ^ 4;                // row 32+lq

  // ---- stage Q once (kvh==0 waves): head wh, rows q0..q0+31; row = 8p+(l>>3)
  if (kvh == 0) {
#pragma unroll
    for (int p = 0; p < 4; p++)
      gll16(qh + (size_t)(q0 + 8*p + (l >> 3)) * DM + h * HD + (sch ^ p) * 8,
            Qs + wh * 2048 + p * 512);
  }
  // ---- stage first K/V tile of this wave's half; row = 16wh+8j+(l>>3)
  f16* KsH = Ks + kvh * 8192;
  f16* VsH = Vs + kvh * 8192;
#pragma unroll
  for (int j = 0; j < 2; j++) {
    const int row = 16*wh + 8*j + (l >> 3);
    const int sc = sch ^ (2*wh + j);
    gll16(kh + (size_t)(kvb + row) * HD + sc * 8, KsH + (2*wh + j) * 512);
    gll16(vt + (size_t)row * S + kvb + sc * 8,    VsH + (2*wh + j) * 512);
  }
  wait_vm0();
  __syncthreads();

  f32x16 acc0 = {}, acc1 = {};
  float mrun = -1e29f, lsum = 0.f;
  const f16* QsW = Qs + wh * 2048;

  for (int it = 0; it < NIT; ++it) {
    const int cur = it & 1;
    const int wd = (kvb >> 5) + it * 2;
    u32 mw0 = mb[(size_t)wd * S + q0 + lq];
    u32 mw1 = mb[(size_t)(wd + 1) * S + q0 + lq];
    if (it + 1 < NIT) {
      const int nk = kvb + (it + 1) * KB;
#pragma unroll
      for (int j = 0; j < 2; j++) {
        const int row = 16*wh + 8*j + (l >> 3);
        const int sc = sch ^ (2*wh + j);
        gll16(kh + (size_t)(nk + row) * HD + sc * 8, KsH + (cur ^ 1) * 4096 + (2*wh + j) * 512);
        gll16(vt + (size_t)row * S + nk + sc * 8,    VsH + (cur ^ 1) * 4096 + (2*wh + j) * 512);
      }
    }
    // QK^T swapped: A = K rows (kv), B = Q  -> t[kv][q], lane col q = lq
    f32x16 t0 = {}, t1 = {};
    const f16* KT = KsH + cur * 4096;
    __builtin_amdgcn_s_setprio(1);
#pragma unroll
    for (int c = 0; c < 4; c++) {
      const int u = hi + 2 * c;
      f16x8 qfc = *(const f16x8*)(QsW + lq * 64 + ((u ^ s0) << 3));
      f16x8 kf0 = *(const f16x8*)(KT + lq * 64        + ((u ^ s0) << 3));
      f16x8 kf1 = *(const f16x8*)(KT + (32 + lq) * 64 + ((u ^ s1) << 3));
      t0 = __builtin_amdgcn_mfma_f32_32x32x16_f16(kf0, qfc, t0, 0, 0, 0);
      t1 = __builtin_amdgcn_mfma_f32_32x32x16_f16(kf1, qfc, t1, 0, 0, 0);
    }
    __builtin_amdgcn_s_setprio(0);
    // mask -> -1e30 before max
    const u32 b0 = mw0 >> (4 * hi), b1 = mw1 >> (4 * hi);
#pragma unroll
    for (int r = 0; r < 16; r++) {
      const int bp = (r & 3) + 8 * (r >> 2);
      t0[r] = ((b0 >> bp) & 1) ? -1e30f : t0[r];
      t1[r] = ((b1 >> bp) & 1) ? -1e30f : t1[r];
    }
    // row max (q = lq), v_max3 tree
    float z0 = MAX3(t0[0], t0[1],  t0[2]),  z1 = MAX3(t0[3],  t0[4],  t0[5]);
    float z2 = MAX3(t0[6], t0[7],  t0[8]),  z3 = MAX3(t0[9],  t0[10], t0[11]);
    float z4 = MAX3(t0[12],t0[13], t0[14]), z5 = MAX3(t0[15], t1[0],  t1[1]);
    float z6 = MAX3(t1[2], t1[3],  t1[4]),  z7 = MAX3(t1[5],  t1[6],  t1[7]);
    float z8 = MAX3(t1[8], t1[9],  t1[10]), z9 = MAX3(t1[11], t1[12], t1[13]);
    float za = fmaxf(t1[14], t1[15]);
    float y0 = MAX3(z0, z1, z2), y1 = MAX3(z3, z4, z5), y2 = MAX3(z6, z7, z8);
    float pmax = MAX3(y0, y1, fmaxf(y2, fmaxf(z9, za)));
    pmax = fmaxf(pmax, __shfl_xor(pmax, 32));
    if (!__all(pmax <= mrun + 11.6f)) {    // defer-max (log2 domain); shuffle-free rescale
      float mn = fmaxf(mrun, pmax);
      float sc = exp2n(mrun - mn);
      mrun = mn; lsum *= sc;
#pragma unroll
      for (int r = 0; r < 16; r++) { acc0[r] *= sc; acc1[r] *= sc; }
    }
#pragma unroll
    for (int r = 0; r < 16; r++) {
      t0[r] = exp2n(t0[r] - mrun);
      t1[r] = exp2n(t1[r] - mrun);
    }
    {
      float a0s = 0.f, a1s = 0.f, a2s = 0.f, a3s = 0.f;
#pragma unroll
      for (int r = 0; r < 16; r += 4) {
        a0s += t0[r] + t1[r];       a1s += t0[r+1] + t1[r+1];
        a2s += t0[r+2] + t1[r+2];   a3s += t0[r+3] + t1[r+3];
      }
      float rs = (a0s + a1s) + (a2s + a3s);
      rs += __shfl_xor(rs, 32);
      lsum += rs;
    }
    // PV (O^T): per c build pa = P[kv=16c+8hi+e][q=lq] via pkrtz+permlane
    const f16* VT = VsH + cur * 4096;
#pragma unroll
    for (int c = 0; c < 4; c++) {
      const int cc = c & 1;
      u32 w0, w1, w2, w3;
      if (c < 2) {
        w0 = pkrtz(t0[8*cc + 0], t0[8*cc + 1]);  w2 = pkrtz(t0[8*cc + 4], t0[8*cc + 5]);
        w1 = pkrtz(t0[8*cc + 2], t0[8*cc + 3]);  w3 = pkrtz(t0[8*cc + 6], t0[8*cc + 7]);
      } else {
        w0 = pkrtz(t1[8*cc + 0], t1[8*cc + 1]);  w2 = pkrtz(t1[8*cc + 4], t1[8*cc + 5]);
        w1 = pkrtz(t1[8*cc + 2], t1[8*cc + 3]);  w3 = pkrtz(t1[8*cc + 6], t1[8*cc + 7]);
      }
      asm volatile("v_permlane32_swap_b32 %0, %1" : "+v"(w0), "+v"(w2));
      asm volatile("v_permlane32_swap_b32 %0, %1" : "+v"(w1), "+v"(w3));
      u32x4 aw = { w0, w1, w2, w3 };
      f16x8 pa = __builtin_bit_cast(f16x8, aw);
      const int u = hi + 2 * c;
      f16x8 v0 = *(const f16x8*)(VT + lq * 64        + ((u ^ s0) << 3));
      f16x8 v1 = *(const f16x8*)(VT + (32 + lq) * 64 + ((u ^ s1) << 3));
      __builtin_amdgcn_s_setprio(1);
      acc0 = __builtin_amdgcn_mfma_f32_32x32x16_f16(v0, pa, acc0, 0, 0, 0);
      acc1 = __builtin_amdgcn_mfma_f32_32x32x16_f16(v1, pa, acc1, 0, 0, 0);
      __builtin_amdgcn_s_setprio(0);
    }
    wait_vm0();
    __syncthreads();
  }

  // ---- merge halves via LDS overlay; acc layout: O^T[d][q=lq] ----
  if (kvh == 1) {
#pragma unroll
    for (int r = 0; r < 16; r++) {
      const int d0 = (r & 3) + 8 * (r >> 2) + 4 * hi;
      Macc[wh * 2048 + d0 * 32 + lq]        = acc0[r];
      Macc[wh * 2048 + (d0 + 32) * 32 + lq] = acc1[r];
    }
    if (hi == 0) {
      Mml[wh * 64 + lq]      = mrun;
      Mml[wh * 64 + 32 + lq] = lsum;
    }
  }
  __syncthreads();
  if (kvh == 0) {
    const float mB = Mml[wh * 64 + lq];
    const float lB = Mml[wh * 64 + 32 + lq];
    const float mS = fmaxf(mrun, mB);
    const float eA = exp2n(mrun - mS), eB = exp2n(mB - mS);
    const float inv = 1.f / (lsum * eA + lB * eB);
    const float fA = eA * inv, fB = eB * inv;
    const size_t base = (size_t)(q0 + lq) * DM + h * HD;
#pragma unroll
    for (int g = 0; g < 4; g++) {
      f16x4 o0, o1;
#pragma unroll
      for (int j = 0; j < 4; j++) {
        const int r = 4 * g + j, d0 = j + 8 * g + 4 * hi;
        o0[j] = (f16)(acc0[r] * fA + Macc[wh * 2048 + d0 * 32 + lq] * fB);
        o1[j] = (f16)(acc1[r] * fA + Macc[wh * 2048 + (d0 + 32) * 32 + lq] * fB);
      }
      *(f16x4*)(att + base + 8 * g + 4 * hi)      = o0;
      *(f16x4*)(att + base + 32 + 8 * g + 4 * hi) = o1;
    }
  }
}

extern "C" void kernel_launch(void* const* d_in, const int* in_sizes, int n_in,
                              void* d_out, int out_size, void* d_ws, size_t ws_size,
                              hipStream_t stream)
{
  const float* q  = (const float*)d_in[0];
  const float* k  = (const float*)d_in[1];
  const float* v  = (const float*)d_in[2];
  const int*  msk = (const int*)d_in[3];
  const float* Wq = (const float*)d_in[4];
  const float* bq = (const float*)d_in[5];
  const float* Wk = (const float*)d_in[6];
  const float* bk = (const float*)d_in[7];
  const float* Wv = (const float*)d_in[8];
  const float* bv = (const float*)d_in[9];
  const float* Wo = (const float*)d_in[10];
  const float* bo = (const float*)d_in[11];

  float* out = (float*)d_out;                 // [4096][1024]
  float* khf = out + (size_t)S * DM;          // [4096][64]
  float* vhf = khf + (size_t)S * HD;          // [4096][64]

  char* ws = (char*)d_ws;
  f16* Wq_t = (f16*)(ws);                               // [1024][1024]
  f16* Wo_t = (f16*)(ws + (2u  << 20));                 // [1024][1024]
  f16* Wk_t = (f16*)(ws + (4u  << 20));                 // [64][1024]
  f16* Wv_t = (f16*)(ws + (4u  << 20) + (128u << 10));  // [64][1024]
  f16* qhp  = (f16*)(ws + (4u  << 20) + (256u << 10));  // [4096][1024] (log2e-scaled)
  f16* khp  = (f16*)(ws + (12u << 20) + (256u << 10));  // [4096][64]
  f16* vtp  = (f16*)(ws + (12u << 20) + (768u << 10));  // [64][4096]
  f16* attp = (f16*)(ws + (13u << 20) + (256u << 10));  // [4096][1024]
  u32* mbp  = (u32*)(ws + (21u << 20) + (256u << 10));  // [128][4096] transposed bits

  k_tcvt<<<dim3(32, 32), 256, 0, stream>>>(Wq, Wq_t, 1024, 1024);
  k_tcvt<<<dim3(32, 32), 256, 0, stream>>>(Wo, Wo_t, 1024, 1024);
  k_tcvt<<<dim3(2, 32),  256, 0, stream>>>(Wk, Wk_t, 1024, 64);
  k_tcvt<<<dim3(2, 32),  256, 0, stream>>>(Wv, Wv_t, 1024, 64);
  k_maskbits<<<2048, 256, 0, stream>>>(msk, mbp);

  k_gemm<128, 2, 2, false, 0><<<dim3(32, 8), 256, 0, stream>>>(q, nullptr, Wq_t, bq, nullptr, qhp);
  k_gemm_kv<<<dim3(128, 2), 256, 0, stream>>>(k, v, Wk_t, Wv_t, bk, bv, khf, vhf, khp, vtp);

  k_attn<<<dim3(S / 32, 4), 512, 0, stream>>>(qhp, khp, vtp, mbp, attp);

  k_gemm<128, 2, 2, true, 1><<<dim3(32, 8), 256, 0, stream>>>(nullptr, attp, Wo_t, bo, out, nullptr);
}